// Round 1
// baseline (31861.871 us; speedup 1.0000x reference)
//
#include <hip/hip_runtime.h>
#include <math.h>

// ToxicityLSTM: 2-layer LSTM (B=64, T=1024, H=256, gate order i,j,f,o,
// forget bias 1.0) + linear head (256->6) + sigmoid + threshold.
//
// Design: persistent cooperative-style kernel, 256 blocks x 256 threads.
//   - Software-pipelined layers: superstep s runs layer1@t=s (blocks 0..127)
//     and layer2@t=s-1 (blocks 128..255) concurrently -> 1 sync/superstep.
//   - Thread = (b, u, k-half): computes all 4 gate dot-product halves for one
//     hidden unit, combines halves via LDS, then does the LSTM update locally.
//     Cell state c lives in registers (same thread owns (b,u) every step).
//   - h1/h2 cross-block state: double-buffered in d_ws, accessed with
//     device-scope relaxed atomics (bypasses L1/L2 -> no stale reads, and no
//     acquire-fence cache invalidation that would evict L2-resident weights).
//   - Barrier: per-superstep counters (fresh slot each step, memset at launch
//     -> deterministic under graph replay). Dependencies are batch-group
//     local, so 4 independent 64-arrival barriers instead of one 256-arrival.

#define BB 64
#define TT 1024
#define HH 256
#define G4 1024                    // 4*H
#define NBLK_PER_TASK 128
#define NTHREADS 256
#define NGRP 4                     // batch groups (16 b each)
#define ARRIVALS 64                // 32 layer1-blocks + 32 layer2-blocks per group
#define NSLOTS (TT + 1)
#define BAR_STRIDE 8               // ints per counter (32B apart)
#define BAR_INTS (NSLOTS * NGRP * BAR_STRIDE)
#define BAR_BYTES ((((size_t)BAR_INTS * 4) + 255) & ~(size_t)255)
#define HBUF_FLOATS (BB * HH)      // 16384 floats per h buffer
#define WS_NEEDED (BAR_BYTES + (size_t)4 * HBUF_FLOATS * 4)

__device__ __forceinline__ float coh_load(const float* p) {
  return __hip_atomic_load(p, __ATOMIC_RELAXED, __HIP_MEMORY_SCOPE_AGENT);
}
__device__ __forceinline__ void coh_store(float* p, float v) {
  __hip_atomic_store(p, v, __ATOMIC_RELAXED, __HIP_MEMORY_SCOPE_AGENT);
}
__device__ __forceinline__ float sigmoidf_(float v) {
  return 1.f / (1.f + expf(-v));
}

__global__ __launch_bounds__(NTHREADS, 1) void lstm2_persistent(
    const float* __restrict__ x,
    const float* __restrict__ k0, const float* __restrict__ b0,
    const float* __restrict__ k1, const float* __restrict__ b1,
    float* __restrict__ hws, int* __restrict__ bar)
{
  const int blk   = blockIdx.x;
  const int taskB = (blk >= NBLK_PER_TASK) ? 1 : 0;   // layer2 blocks
  const int tblk  = taskB ? blk - NBLK_PER_TASK : blk;
  const int bgrp  = tblk >> 5;       // 4 groups of 16 batch rows
  const int ugrp  = tblk & 31;       // 32 groups of 8 hidden units

  const int tid = threadIdx.x;
  const int ul  = tid & 7;           // unit within group (lane-fast: W coalescing)
  const int bl  = (tid >> 3) & 15;   // batch within group
  const int kh  = tid >> 7;          // k-half: wave-uniform -> no divergence

  const int b = bgrp * 16 + bl;
  const int u = ugrp * 8 + ul;

  const float* W    = taskB ? k1 : k0;
  const float* bias = taskB ? b1 : b0;
  // This thread's K-half of the weight matrix, at its unit column.
  const float* Wcol = W + (size_t)(kh ? 256 : 0) * G4 + u;

  float bias0v = 0.f, bias1v = 0.f, bias2v = 0.f, bias3v = 0.f;
  if (kh == 0) {
    bias0v = bias[u];
    bias1v = bias[256 + u];
    bias2v = bias[512 + u];
    bias3v = bias[768 + u];
  }

  float* h1b0 = hws;
  float* h1b1 = hws + HBUF_FLOATS;
  float* h2b0 = hws + 2 * HBUF_FLOATS;
  float* h2b1 = hws + 3 * HBUF_FLOATS;

  float cst = 0.f;                   // cell state: register-resident
  __shared__ float4 sm[NTHREADS];

  for (int s = 0; s <= TT; ++s) {
    const int active = taskB ? (s >= 1) : (s < TT);
    if (active) {
      const int t = taskB ? (s - 1) : s;
      float g0 = bias0v, g1 = bias1v, g2 = bias2v, g3 = bias3v;

      if (!taskB && kh == 0) {
        // layer1 x-part: plain (cacheable) vectorized loads of input x
        const float* row = x + ((size_t)b * TT + t) * HH;
        const float* wr = Wcol;
        #pragma unroll 2
        for (int k = 0; k < HH; k += 4) {
          float4 a = *(const float4*)(row + k);
          g0 = fmaf(a.x, wr[0], g0); g1 = fmaf(a.x, wr[256], g1);
          g2 = fmaf(a.x, wr[512], g2); g3 = fmaf(a.x, wr[768], g3); wr += G4;
          g0 = fmaf(a.y, wr[0], g0); g1 = fmaf(a.y, wr[256], g1);
          g2 = fmaf(a.y, wr[512], g2); g3 = fmaf(a.y, wr[768], g3); wr += G4;
          g0 = fmaf(a.z, wr[0], g0); g1 = fmaf(a.z, wr[256], g1);
          g2 = fmaf(a.z, wr[512], g2); g3 = fmaf(a.z, wr[768], g3); wr += G4;
          g0 = fmaf(a.w, wr[0], g0); g1 = fmaf(a.w, wr[256], g1);
          g2 = fmaf(a.w, wr[512], g2); g3 = fmaf(a.w, wr[768], g3); wr += G4;
        }
      } else {
        // recurrent operand: device-coherent loads (cross-block producer)
        const float* row;
        if (!taskB) {
          row = (((s - 1) & 1) ? h1b1 : h1b0) + b * HH;   // h1(s-1)
        } else if (kh == 0) {
          row = (((s - 1) & 1) ? h1b1 : h1b0) + b * HH;   // h1(s-1)
        } else {
          row = ((s & 1) ? h2b1 : h2b0) + b * HH;         // h2(s-2)
        }
        const float* wr = Wcol;
        #pragma unroll 4
        for (int k = 0; k < HH; ++k) {
          float a = coh_load(row + k);
          g0 = fmaf(a, wr[0], g0); g1 = fmaf(a, wr[256], g1);
          g2 = fmaf(a, wr[512], g2); g3 = fmaf(a, wr[768], g3);
          wr += G4;
        }
      }

      // combine the two K-halves (partner is in the other wave-pair -> LDS)
      sm[tid] = make_float4(g0, g1, g2, g3);
      __syncthreads();
      float4 p = sm[tid ^ 128];
      g0 += p.x; g1 += p.y; g2 += p.z; g3 += p.w;

      // LSTM cell update (gate order i, j, f, o; forget bias 1.0)
      float ig = sigmoidf_(g0);
      float jt = tanhf(g1);
      float fg = sigmoidf_(g2 + 1.0f);
      float og = sigmoidf_(g3);
      cst = fg * cst + ig * jt;
      float hn = og * tanhf(cst);

      if (kh == 0) {
        float* hb;
        if (!taskB) hb = ((s & 1) ? h1b1 : h1b0);          // write h1(s)
        else        hb = (((s - 1) & 1) ? h2b1 : h2b0);    // write h2(s-1)
        coh_store(hb + b * HH + u, hn);
      }
    }

    // ---- per-batch-group grid barrier (64 arrivals) ----
    __syncthreads();   // also drains this block's stores (waitcnt before s_barrier)
    if (tid == 0) {
      int* ctr = bar + ((size_t)s * NGRP + bgrp) * BAR_STRIDE;
      __hip_atomic_fetch_add(ctr, 1, __ATOMIC_RELEASE, __HIP_MEMORY_SCOPE_AGENT);
      while (__hip_atomic_load(ctr, __ATOMIC_RELAXED, __HIP_MEMORY_SCOPE_AGENT)
             < ARRIVALS) {
        __builtin_amdgcn_s_sleep(1);
      }
    }
    __syncthreads();
  }
}

// Head: logits = h2_last @ w_out + b_out; sigmoid; threshold.
__global__ void head_kernel(const float* __restrict__ h2last,
                            const float* __restrict__ w_out,
                            const float* __restrict__ b_out,
                            float* __restrict__ out)
{
  int tid = threadIdx.x;
  if (tid >= 384) return;
  int bb = tid / 6, c = tid % 6;
  float acc = b_out[c];
  const float* hr = h2last + bb * HH;
  #pragma unroll 4
  for (int uu = 0; uu < HH; ++uu) acc = fmaf(hr[uu], w_out[uu * 6 + c], acc);
  out[tid] = acc;                         // logits
  float sg = 1.f / (1.f + expf(-acc));
  out[384 + tid] = sg;                    // sigmoid output
  out[768 + tid] = (sg > 0.5f) ? 1.f : 0.f;  // prediction
}

extern "C" void kernel_launch(void* const* d_in, const int* in_sizes, int n_in,
                              void* d_out, int out_size, void* d_ws, size_t ws_size,
                              hipStream_t stream) {
  const float* x     = (const float*)d_in[0];
  const float* k0    = (const float*)d_in[1];
  const float* b0    = (const float*)d_in[2];
  const float* k1    = (const float*)d_in[3];
  const float* b1    = (const float*)d_in[4];
  const float* w_out = (const float*)d_in[5];
  const float* b_out = (const float*)d_in[6];
  float* out = (float*)d_out;

  if (ws_size < WS_NEEDED) return;  // workspace too small -> visible failure

  // Reset barrier counters + zero-init h state (h(-1) = 0) every call so the
  // captured graph replays identically.
  hipMemsetAsync(d_ws, 0, WS_NEEDED, stream);

  int*   bar = (int*)d_ws;
  float* hws = (float*)((char*)d_ws + BAR_BYTES);

  lstm2_persistent<<<2 * NBLK_PER_TASK, NTHREADS, 0, stream>>>(
      x, k0, b0, k1, b1, hws, bar);

  // h2(T-1) lives in buffer [(T-1)&1] = buffer 1
  head_kernel<<<1, 384, 0, stream>>>(hws + 3 * HBUF_FLOATS, w_out, b_out, out);
}

// Round 2
// 9163.281 us; speedup vs baseline: 3.4771x; 3.4771x over previous
//
#include <hip/hip_runtime.h>
#include <math.h>

// ToxicityLSTM: 2-layer LSTM (B=64, T=1024, H=256, gates i,j,f,o, forget
// bias 1.0) + linear head (256->6) + sigmoid + threshold.
//
// Round 2: LDS-resident weights + LDS-staged operand panel + register tiling.
//   - One-time transpose: WT[u][4 gates][512 k] (k-contiguous) in d_ws.
//   - Persistent kernel: 256 blocks x 256 threads (1 block/CU), software-
//     pipelined layers (blocks 0..127 layer1 @ t=s, 128..255 layer2 @ t=s-1),
//     per-batch-group 64-arrival grid barrier per superstep (proven in R1).
//   - Per block: 8 units x 16 batch. Weight strip (8u x 4g x 512k = 64 KB)
//     loaded into LDS ONCE before the time loop.
//   - Per step: stage [16 b][512 k] operand panel (x||h1 or h1||h2) into LDS
//     with coalesced float4 loads; coherent loads batched in one asm block
//     (8 in flight, single vmcnt) for cross-XCD h buffers.
//   - Thread = (ul 8, bt 4, kq 8): 4 b x 4 gates accumulators in registers,
//     64 k slice; inner loop = 64 ds_read_b128 (W) + 64 ds_read_b128 (h)
//     + 1024 FMA. 8-way k-partials combined via LDS; threads 0..127 finish
//     LSTM update (c in registers) and store h coherently.

#define BB 64
#define TT 1024
#define HH 256
#define NTHREADS 256
#define NGRP 4
#define ARRIVALS 64
#define NSLOTS (TT + 1)
#define BAR_STRIDE 8
#define BAR_INTS (NSLOTS * NGRP * BAR_STRIDE)
#define BAR_BYTES ((((size_t)BAR_INTS * 4) + 255) & ~(size_t)255)
#define HBUF_FLOATS (BB * HH)          // 16384 floats per h buffer
#define WT_FLOATS (256 * 4 * 512)      // 524288 floats per layer
#define WS_NEEDED (BAR_BYTES + (size_t)4 * HBUF_FLOATS * 4 + (size_t)2 * WT_FLOATS * 4)

#define HPAD 516                       // padded row (floats) for hstage
#define WUPAD 2052                     // padded per-unit stride (floats) for wlds

typedef float f32x4 __attribute__((ext_vector_type(4)));

__device__ __forceinline__ void coh_store(float* p, float v) {
  __hip_atomic_store(p, v, __ATOMIC_RELAXED, __HIP_MEMORY_SCOPE_AGENT);
}

// 8 coherent (cross-XCD) float4 loads in flight, one vmcnt drain.
__device__ __forceinline__ void coh_load4x8(
    const float* p0, const float* p1, const float* p2, const float* p3,
    const float* p4, const float* p5, const float* p6, const float* p7,
    f32x4& a0, f32x4& a1, f32x4& a2, f32x4& a3,
    f32x4& a4, f32x4& a5, f32x4& a6, f32x4& a7) {
  asm volatile(
      "global_load_dwordx4 %0, %8, off sc0 sc1\n\t"
      "global_load_dwordx4 %1, %9, off sc0 sc1\n\t"
      "global_load_dwordx4 %2, %10, off sc0 sc1\n\t"
      "global_load_dwordx4 %3, %11, off sc0 sc1\n\t"
      "global_load_dwordx4 %4, %12, off sc0 sc1\n\t"
      "global_load_dwordx4 %5, %13, off sc0 sc1\n\t"
      "global_load_dwordx4 %6, %14, off sc0 sc1\n\t"
      "global_load_dwordx4 %7, %15, off sc0 sc1\n\t"
      "s_waitcnt vmcnt(0)"
      : "=&v"(a0), "=&v"(a1), "=&v"(a2), "=&v"(a3),
        "=&v"(a4), "=&v"(a5), "=&v"(a6), "=&v"(a7)
      : "v"(p0), "v"(p1), "v"(p2), "v"(p3),
        "v"(p4), "v"(p5), "v"(p6), "v"(p7)
      : "memory");
}

// One-time weight transpose: src [512 k][4 g * 256 u] -> dst [256 u][4 g][512 k]
__global__ void transpose_w(const float* __restrict__ src, float* __restrict__ dst) {
  __shared__ float t[64][65];
  const int g  = blockIdx.x;   // 4
  const int kt = blockIdx.y;   // 8 tiles over 512 k
  const int ut = blockIdx.z;   // 4 tiles over 256 u
  const int tx = threadIdx.x & 63;
  const int ty = threadIdx.x >> 6;
  #pragma unroll
  for (int r = ty; r < 64; r += 4)
    t[r][tx] = src[(size_t)(kt * 64 + r) * 1024 + g * 256 + ut * 64 + tx];
  __syncthreads();
  #pragma unroll
  for (int r = ty; r < 64; r += 4)
    dst[((size_t)(ut * 64 + r) * 4 + g) * 512 + kt * 64 + tx] = t[tx][r];
}

__global__ __launch_bounds__(NTHREADS, 1) void lstm2_persistent(
    const float* __restrict__ x,
    const float* __restrict__ b0, const float* __restrict__ b1,
    const float* __restrict__ wt0, const float* __restrict__ wt1,
    float* __restrict__ hws, int* __restrict__ bar)
{
  __shared__ float wlds[8 * WUPAD];      // 65664 B  weight strip
  __shared__ float hstage[16 * HPAD];    // 33024 B  operand panel
  __shared__ f32x4 part[8 * 16 * 8];     // 16384 B  k-partials

  const int blk   = blockIdx.x;
  const int taskB = (blk >= 128) ? 1 : 0;              // layer2 blocks
  const int tblk  = taskB ? blk - 128 : blk;
  const int bgrp  = tblk >> 5;                          // 4 groups of 16 b
  const int ugrp  = tblk & 31;                          // 32 groups of 8 u

  const int tid = threadIdx.x;
  const int ul  = tid & 7;
  const int bt  = (tid >> 3) & 3;
  const int kq  = tid >> 5;

  // staging role: fixed column range, 8 rows (even rows for tid<128, odd after)
  const int  cl  = (tid & 127) * 4;    // 0..508
  const int  r0  = tid >> 7;           // 0/1
  const bool opA = (cl < 256);

  const float* WT   = taskB ? wt1 : wt0;
  const float* bias = taskB ? b1 : b0;

  // ---- load weight strip into LDS once ----
  {
    const float* src = WT + (size_t)ugrp * 8 * 2048;
    #pragma unroll
    for (int i = 0; i < 16; ++i) {
      const int f = (i * NTHREADS + tid) * 4;
      f32x4 v = *(const f32x4*)(src + f);
      const int uu = f >> 11, rem = f & 2047;
      *(f32x4*)&wlds[uu * WUPAD + rem] = v;
    }
  }

  // ---- finisher state (threads 0..127 own one (b,u) pair) ----
  float bi = 0.f, bj = 0.f, bfv = 0.f, bo = 0.f;
  int fb = 0, fu = 0;
  if (tid < 128) {
    const int ful = tid & 7, fbl = tid >> 3;
    fu = ugrp * 8 + ful;
    fb = bgrp * 16 + fbl;
    bi  = bias[fu];
    bj  = bias[256 + fu];
    bfv = bias[512 + fu];
    bo  = bias[768 + fu];
  }
  float cst = 0.f;

  float* h1b0 = hws;
  float* h1b1 = hws + HBUF_FLOATS;
  float* h2b0 = hws + 2 * HBUF_FLOATS;
  float* h2b1 = hws + 3 * HBUF_FLOATS;

  __syncthreads();  // wlds ready

  for (int s = 0; s <= TT; ++s) {
    const int active = taskB ? (s >= 1) : (s < TT);
    if (active) {
      const int t = taskB ? (s - 1) : s;
      const float* h1prev = ((s - 1) & 1) ? h1b1 : h1b0;   // h1(s-1)

      // ---- stage operand panel [16][512] into LDS ----
      f32x4 v0, v1, v2, v3, v4, v5, v6, v7;
      if (!taskB && opA) {
        // x[b][t][cl..cl+3] for 8 rows: fully coalesced plain loads
        const float* base = x + (size_t)t * HH + cl;
        v0 = *(const f32x4*)(base + (size_t)(bgrp * 16 + 0 + r0) * (TT * HH));
        v1 = *(const f32x4*)(base + (size_t)(bgrp * 16 + 2 + r0) * (TT * HH));
        v2 = *(const f32x4*)(base + (size_t)(bgrp * 16 + 4 + r0) * (TT * HH));
        v3 = *(const f32x4*)(base + (size_t)(bgrp * 16 + 6 + r0) * (TT * HH));
        v4 = *(const f32x4*)(base + (size_t)(bgrp * 16 + 8 + r0) * (TT * HH));
        v5 = *(const f32x4*)(base + (size_t)(bgrp * 16 + 10 + r0) * (TT * HH));
        v6 = *(const f32x4*)(base + (size_t)(bgrp * 16 + 12 + r0) * (TT * HH));
        v7 = *(const f32x4*)(base + (size_t)(bgrp * 16 + 14 + r0) * (TT * HH));
      } else {
        const float* src;
        if (!taskB) {
          src = h1prev + (size_t)(bgrp * 16 + r0) * HH + (cl - 256);
        } else if (opA) {
          src = h1prev + (size_t)(bgrp * 16 + r0) * HH + cl;
        } else {
          const float* h2prev = (s & 1) ? h2b1 : h2b0;     // h2(s-2)
          src = h2prev + (size_t)(bgrp * 16 + r0) * HH + (cl - 256);
        }
        coh_load4x8(src, src + 512, src + 1024, src + 1536,
                    src + 2048, src + 2560, src + 3072, src + 3584,
                    v0, v1, v2, v3, v4, v5, v6, v7);
      }
      {
        float* d = &hstage[r0 * HPAD + cl];
        *(f32x4*)(d + 0 * 2 * HPAD) = v0;
        *(f32x4*)(d + 1 * 2 * HPAD) = v1;
        *(f32x4*)(d + 2 * 2 * HPAD) = v2;
        *(f32x4*)(d + 3 * 2 * HPAD) = v3;
        *(f32x4*)(d + 4 * 2 * HPAD) = v4;
        *(f32x4*)(d + 5 * 2 * HPAD) = v5;
        *(f32x4*)(d + 6 * 2 * HPAD) = v6;
        *(f32x4*)(d + 7 * 2 * HPAD) = v7;
      }
      __syncthreads();

      // ---- GEMV inner: 4 b x 4 g accumulators, 64-k slice ----
      float acc[4][4];
      #pragma unroll
      for (int j2 = 0; j2 < 4; ++j2)
        #pragma unroll
        for (int g = 0; g < 4; ++g) acc[j2][g] = 0.f;

      const float* wbase = &wlds[ul * WUPAD];
      const int k0 = kq * 64;
      #pragma unroll 2
      for (int kk = 0; kk < 64; kk += 4) {
        f32x4 w[4];
        #pragma unroll
        for (int g = 0; g < 4; ++g)
          w[g] = *(const f32x4*)(wbase + g * 512 + k0 + kk);
        #pragma unroll
        for (int j2 = 0; j2 < 4; ++j2) {
          const f32x4 h4 = *(const f32x4*)&hstage[(bt * 4 + j2) * HPAD + k0 + kk];
          #pragma unroll
          for (int g = 0; g < 4; ++g) {
            acc[j2][g] = fmaf(h4[0], w[g][0], acc[j2][g]);
            acc[j2][g] = fmaf(h4[1], w[g][1], acc[j2][g]);
            acc[j2][g] = fmaf(h4[2], w[g][2], acc[j2][g]);
            acc[j2][g] = fmaf(h4[3], w[g][3], acc[j2][g]);
          }
        }
      }

      // ---- k-combine via LDS partials ----
      #pragma unroll
      for (int j2 = 0; j2 < 4; ++j2) {
        f32x4 p = { acc[j2][0], acc[j2][1], acc[j2][2], acc[j2][3] };
        part[(kq * 16 + bt * 4 + j2) * 8 + ul] = p;
      }
      __syncthreads();

      if (tid < 128) {
        const int fbl = tid >> 3, ful = tid & 7;
        float gi = bi, gj = bj, gf = bfv, go = bo;
        #pragma unroll
        for (int q = 0; q < 8; ++q) {
          f32x4 p = part[(q * 16 + fbl) * 8 + ful];
          gi += p[0]; gj += p[1]; gf += p[2]; go += p[3];
        }
        const float ig = 1.f / (1.f + expf(-gi));
        const float jt = tanhf(gj);
        const float fg = 1.f / (1.f + expf(-(gf + 1.0f)));
        const float og = 1.f / (1.f + expf(-go));
        cst = fg * cst + ig * jt;
        const float hn = og * tanhf(cst);
        float* hbout;
        if (!taskB) hbout = (s & 1) ? h1b1 : h1b0;          // h1(s)
        else        hbout = ((s - 1) & 1) ? h2b1 : h2b0;    // h2(s-1)
        coh_store(hbout + (size_t)fb * HH + fu, hn);
      }
    }

    // ---- per-batch-group grid barrier (64 arrivals) ----
    __syncthreads();
    if (tid == 0) {
      int* ctr = bar + ((size_t)s * NGRP + bgrp) * BAR_STRIDE;
      __hip_atomic_fetch_add(ctr, 1, __ATOMIC_RELEASE, __HIP_MEMORY_SCOPE_AGENT);
      while (__hip_atomic_load(ctr, __ATOMIC_RELAXED, __HIP_MEMORY_SCOPE_AGENT)
             < ARRIVALS) {
        __builtin_amdgcn_s_sleep(1);
      }
    }
    __syncthreads();
  }
}

// Head: logits = h2_last @ w_out + b_out; sigmoid; threshold.
__global__ void head_kernel(const float* __restrict__ h2last,
                            const float* __restrict__ w_out,
                            const float* __restrict__ b_out,
                            float* __restrict__ out)
{
  int tid = threadIdx.x;
  if (tid >= 384) return;
  int bb = tid / 6, c = tid % 6;
  float acc = b_out[c];
  const float* hr = h2last + bb * HH;
  #pragma unroll 4
  for (int uu = 0; uu < HH; ++uu) acc = fmaf(hr[uu], w_out[uu * 6 + c], acc);
  out[tid] = acc;                            // logits
  float sg = 1.f / (1.f + expf(-acc));
  out[384 + tid] = sg;                       // sigmoid output
  out[768 + tid] = (sg > 0.5f) ? 1.f : 0.f;  // prediction
}

extern "C" void kernel_launch(void* const* d_in, const int* in_sizes, int n_in,
                              void* d_out, int out_size, void* d_ws, size_t ws_size,
                              hipStream_t stream) {
  const float* x     = (const float*)d_in[0];
  const float* k0    = (const float*)d_in[1];
  const float* b0    = (const float*)d_in[2];
  const float* k1    = (const float*)d_in[3];
  const float* b1    = (const float*)d_in[4];
  const float* w_out = (const float*)d_in[5];
  const float* b_out = (const float*)d_in[6];
  float* out = (float*)d_out;

  if (ws_size < WS_NEEDED) return;  // visible failure if ws too small

  int*   bar = (int*)d_ws;
  float* hws = (float*)((char*)d_ws + BAR_BYTES);
  float* wt0 = hws + 4 * HBUF_FLOATS;
  float* wt1 = wt0 + WT_FLOATS;

  // Zero barrier counters + h buffers (h(-1)=c(-1)=0) every call: graph-replay
  // deterministic. WT is fully rewritten below.
  hipMemsetAsync(d_ws, 0, BAR_BYTES + (size_t)4 * HBUF_FLOATS * 4, stream);

  transpose_w<<<dim3(4, 8, 4), 256, 0, stream>>>(k0, wt0);
  transpose_w<<<dim3(4, 8, 4), 256, 0, stream>>>(k1, wt1);

  lstm2_persistent<<<256, NTHREADS, 0, stream>>>(x, b0, b1, wt0, wt1, hws, bar);

  // h2(T-1) lives in buffer [(T-1)&1] = buffer 1
  head_kernel<<<1, 384, 0, stream>>>(hws + 3 * HBUF_FLOATS, w_out, b_out, out);
}

// Round 3
// 3969.446 us; speedup vs baseline: 8.0268x; 2.3085x over previous
//
#include <hip/hip_runtime.h>
#include <math.h>

// ToxicityLSTM: 2-layer LSTM (B=64, T=1024, H=256, gates i,j,f,o, forget
// bias 1.0) + linear head (256->6) + sigmoid + threshold.
//
// Round 3: register-resident weights + 8 waves/CU + flag barrier.
//   - Persistent kernel: 256 blocks x 512 threads (1 block/CU guaranteed
//     residency, 8 waves/CU for latency hiding). Blocks 0..127 layer1@t=s,
//     128..255 layer2@t=s-1 (software pipeline, 1 barrier/superstep).
//   - Block = 8 units x 16 batch. Thread (ul=8, kq=16, bt=4): holds W slice
//     [4 gates][32 k] in 128 VGPRs (loop-invariant -> loaded once), computes
//     4 b x 4 g partials over its 32-k slice: 32 ds_read_b128 + 512 FMA/step.
//   - hstage: [16 b][512 k] operand panel in LDS, skewed (k + (k>>5)*4) so
//     the 8 distinct addresses per read instr hit disjoint bank quads.
//   - 16-way k-combine via padded LDS partials; 128 finisher threads own
//     (b,u), keep cell state c in registers, apply gates, store h coherently.
//   - Grid barrier: per-block monotonic step flags (plain coherent store,
//     no atomic RMW serialization); wave 0 polls 64 flags lane-parallel.

#define BB 64
#define TT 1024
#define HH 256
#define NTHREADS 512
#define GRPBLKS 64                    // 32 layer1 + 32 layer2 blocks per bgrp
#define FLAG_STRIDE 16                // ints; 64 B apart
#define FLAG_INTS (4 * GRPBLKS * FLAG_STRIDE)
#define FLAG_BYTES ((((size_t)FLAG_INTS * 4) + 255) & ~(size_t)255)
#define HBUF_FLOATS (BB * HH)         // 16384 floats per h buffer
#define WT_FLOATS (256 * 4 * 512)     // 524288 floats per layer
#define WS_NEEDED (FLAG_BYTES + (size_t)4 * HBUF_FLOATS * 4 + (size_t)2 * WT_FLOATS * 4)

#define HROW 576                      // skewed row stride (floats)

typedef float f32x4 __attribute__((ext_vector_type(4)));

__device__ __forceinline__ void coh_store(float* p, float v) {
  __hip_atomic_store(p, v, __ATOMIC_RELAXED, __HIP_MEMORY_SCOPE_AGENT);
}

// 4 coherent (device-scope) float4 loads in flight, one vmcnt drain.
__device__ __forceinline__ void coh_load4(
    const float* p0, const float* p1, const float* p2, const float* p3,
    f32x4& a0, f32x4& a1, f32x4& a2, f32x4& a3) {
  asm volatile(
      "global_load_dwordx4 %0, %4, off sc0 sc1\n\t"
      "global_load_dwordx4 %1, %5, off sc0 sc1\n\t"
      "global_load_dwordx4 %2, %6, off sc0 sc1\n\t"
      "global_load_dwordx4 %3, %7, off sc0 sc1\n\t"
      "s_waitcnt vmcnt(0)"
      : "=&v"(a0), "=&v"(a1), "=&v"(a2), "=&v"(a3)
      : "v"(p0), "v"(p1), "v"(p2), "v"(p3)
      : "memory");
}

// One-time weight transpose: src [512 k][4 g * 256 u] -> dst [256 u][4 g][512 k]
__global__ void transpose_w(const float* __restrict__ src, float* __restrict__ dst) {
  __shared__ float t[64][65];
  const int g  = blockIdx.x;   // 4
  const int kt = blockIdx.y;   // 8 tiles over 512 k
  const int ut = blockIdx.z;   // 4 tiles over 256 u
  const int tx = threadIdx.x & 63;
  const int ty = threadIdx.x >> 6;
  #pragma unroll
  for (int r = ty; r < 64; r += 4)
    t[r][tx] = src[(size_t)(kt * 64 + r) * 1024 + g * 256 + ut * 64 + tx];
  __syncthreads();
  #pragma unroll
  for (int r = ty; r < 64; r += 4)
    dst[((size_t)(ut * 64 + r) * 4 + g) * 512 + kt * 64 + tx] = t[tx][r];
}

__global__ __launch_bounds__(NTHREADS, 2) void lstm2_persistent(
    const float* __restrict__ x,
    const float* __restrict__ b0, const float* __restrict__ b1,
    const float* __restrict__ wt0, const float* __restrict__ wt1,
    float* __restrict__ hws, int* __restrict__ flags)
{
  __shared__ float hstage[16 * HROW];   // 36864 B operand panel (skewed)
  __shared__ f32x4 part[128 * 17];      // 34816 B k-partials (padded)

  const int blk   = blockIdx.x;
  const int taskB = blk >= 128;                 // layer2 blocks
  const int tblk  = taskB ? blk - 128 : blk;
  const int bgrp  = tblk >> 5;                  // 4 groups of 16 b
  const int ublk  = tblk & 31;                  // 32 groups of 8 u

  const int tid = threadIdx.x;
  const int ul  = tid & 7;
  const int kq  = (tid >> 3) & 15;
  const int bt  = tid >> 7;                     // 0..3 (4 batches each)
  const int c   = tid & 127;                    // staging f32x4 column
  const int r0  = tid >> 7;                     // staging base row

  const float* WT   = taskB ? wt1 : wt0;
  const float* bias = taskB ? b1 : b0;

  // ---- loop-invariant weight slice into registers: [4 g][32 k] ----
  f32x4 w[4][8];
  {
    const float* wb = WT + (size_t)(ublk * 8 + ul) * 2048 + kq * 32;
    #pragma unroll
    for (int g = 0; g < 4; ++g)
      #pragma unroll
      for (int cc = 0; cc < 8; ++cc)
        w[g][cc] = *(const f32x4*)(wb + g * 512 + cc * 4);
  }

  // ---- finisher state (threads 0..127 own one (b,u)) ----
  float bi = 0.f, bj = 0.f, bfv = 0.f, bo = 0.f;
  if (tid < 128) {
    const int u = ublk * 8 + (tid & 7);
    bi  = bias[u];
    bj  = bias[256 + u];
    bfv = bias[512 + u];
    bo  = bias[768 + u];
  }
  float cst = 0.f;

  float* h1b0 = hws;
  float* h1b1 = hws + HBUF_FLOATS;
  float* h2b0 = hws + 2 * HBUF_FLOATS;
  float* h2b1 = hws + 3 * HBUF_FLOATS;

  const int dpos = c * 4 + (c >> 3) * 4;        // skewed in-row position

  for (int s = 0; s <= TT; ++s) {
    const bool active = taskB ? (s >= 1) : (s < TT);
    if (active) {
      const int t = taskB ? (s - 1) : s;
      const float* h1prev = ((s - 1) & 1) ? h1b1 : h1b0;   // h1(s-1)

      // ---- stage operand panel [16 b][512 k] into LDS (4 rows/thread) ----
      f32x4 v0, v1, v2, v3;
      if (!taskB && c < 64) {
        // x part: plain cacheable loads, lane-contiguous in k
        const float* bx = x + (size_t)t * HH + c * 4;
        v0 = *(const f32x4*)(bx + (size_t)(bgrp * 16 + r0 + 0)  * ((size_t)TT * HH));
        v1 = *(const f32x4*)(bx + (size_t)(bgrp * 16 + r0 + 4)  * ((size_t)TT * HH));
        v2 = *(const f32x4*)(bx + (size_t)(bgrp * 16 + r0 + 8)  * ((size_t)TT * HH));
        v3 = *(const f32x4*)(bx + (size_t)(bgrp * 16 + r0 + 12) * ((size_t)TT * HH));
      } else {
        const float* src;
        int kk;
        if (!taskB)      { src = h1prev; kk = (c - 64) * 4; }
        else if (c < 64) { src = h1prev; kk = c * 4; }
        else {
          const float* h2prev = (s & 1) ? h2b1 : h2b0;     // h2(s-2)
          src = h2prev; kk = (c - 64) * 4;
        }
        const float* p0 = src + (size_t)(bgrp * 16 + r0) * HH + kk;
        coh_load4(p0, p0 + 4 * HH, p0 + 8 * HH, p0 + 12 * HH, v0, v1, v2, v3);
      }
      *(f32x4*)&hstage[(r0 + 0)  * HROW + dpos] = v0;
      *(f32x4*)&hstage[(r0 + 4)  * HROW + dpos] = v1;
      *(f32x4*)&hstage[(r0 + 8)  * HROW + dpos] = v2;
      *(f32x4*)&hstage[(r0 + 12) * HROW + dpos] = v3;
      __syncthreads();

      // ---- GEMV: 4 b x 4 g accumulators over 32-k slice ----
      float acc[4][4];
      #pragma unroll
      for (int b4 = 0; b4 < 4; ++b4)
        #pragma unroll
        for (int g = 0; g < 4; ++g) acc[b4][g] = 0.f;

      const int kbase = kq * 36;                // skewed slice start
      #pragma unroll
      for (int b4 = 0; b4 < 4; ++b4) {
        const float* hp = &hstage[(bt * 4 + b4) * HROW + kbase];
        #pragma unroll
        for (int cc = 0; cc < 8; ++cc) {
          const f32x4 h4 = *(const f32x4*)(hp + cc * 4);
          #pragma unroll
          for (int g = 0; g < 4; ++g) {
            acc[b4][g] = fmaf(h4[0], w[g][cc][0], acc[b4][g]);
            acc[b4][g] = fmaf(h4[1], w[g][cc][1], acc[b4][g]);
            acc[b4][g] = fmaf(h4[2], w[g][cc][2], acc[b4][g]);
            acc[b4][g] = fmaf(h4[3], w[g][cc][3], acc[b4][g]);
          }
        }
      }

      // ---- 16-way k-combine via padded LDS partials ----
      #pragma unroll
      for (int b4 = 0; b4 < 4; ++b4) {
        f32x4 p = { acc[b4][0], acc[b4][1], acc[b4][2], acc[b4][3] };
        part[((bt * 4 + b4) * 8 + ul) * 17 + kq] = p;
      }
      __syncthreads();

      if (tid < 128) {
        float gi = bi, gj = bj, gf = bfv, go = bo;
        #pragma unroll
        for (int q = 0; q < 16; ++q) {
          const f32x4 p = part[tid * 17 + q];
          gi += p[0]; gj += p[1]; gf += p[2]; go += p[3];
        }
        const float ig = 1.f / (1.f + expf(-gi));
        const float jt = tanhf(gj);
        const float fg = 1.f / (1.f + expf(-(gf + 1.0f)));
        const float og = 1.f / (1.f + expf(-go));
        cst = fg * cst + ig * jt;
        const float hn = og * tanhf(cst);
        float* hbout;
        if (!taskB) hbout = (s & 1) ? h1b1 : h1b0;         // h1(s)
        else        hbout = ((s - 1) & 1) ? h2b1 : h2b0;   // h2(s-1)
        coh_store(hbout + (size_t)(bgrp * 16 + (tid >> 3)) * HH + ublk * 8 + (tid & 7), hn);
      }
    }

    // ---- per-batch-group grid barrier: flag store + lane-parallel poll ----
    if (s < TT) {
      __syncthreads();   // finisher h-stores drained (vmcnt 0) before flag
      if (tid == 0) {
        __hip_atomic_store(&flags[(bgrp * GRPBLKS + (taskB ? 32 : 0) + ublk) * FLAG_STRIDE],
                           s + 1, __ATOMIC_RELAXED, __HIP_MEMORY_SCOPE_AGENT);
      }
      if (tid < GRPBLKS) {
        const int* fp = &flags[(bgrp * GRPBLKS + tid) * FLAG_STRIDE];
        for (;;) {
          const int v = __hip_atomic_load(fp, __ATOMIC_RELAXED, __HIP_MEMORY_SCOPE_AGENT);
          if (__all(v > s)) break;
          __builtin_amdgcn_s_sleep(2);
        }
      }
      __syncthreads();
    }
  }
}

// Head: logits = h2_last @ w_out + b_out; sigmoid; threshold.
__global__ void head_kernel(const float* __restrict__ h2last,
                            const float* __restrict__ w_out,
                            const float* __restrict__ b_out,
                            float* __restrict__ out)
{
  int tid = threadIdx.x;
  if (tid >= 384) return;
  int bb = tid / 6, cc = tid % 6;
  float acc = b_out[cc];
  const float* hr = h2last + bb * HH;
  #pragma unroll 4
  for (int uu = 0; uu < HH; ++uu) acc = fmaf(hr[uu], w_out[uu * 6 + cc], acc);
  out[tid] = acc;                            // logits
  float sg = 1.f / (1.f + expf(-acc));
  out[384 + tid] = sg;                       // sigmoid output
  out[768 + tid] = (sg > 0.5f) ? 1.f : 0.f;  // prediction
}

extern "C" void kernel_launch(void* const* d_in, const int* in_sizes, int n_in,
                              void* d_out, int out_size, void* d_ws, size_t ws_size,
                              hipStream_t stream) {
  const float* x     = (const float*)d_in[0];
  const float* k0    = (const float*)d_in[1];
  const float* b0    = (const float*)d_in[2];
  const float* k1    = (const float*)d_in[3];
  const float* b1    = (const float*)d_in[4];
  const float* w_out = (const float*)d_in[5];
  const float* b_out = (const float*)d_in[6];
  float* out = (float*)d_out;

  if (ws_size < WS_NEEDED) return;  // visible failure if ws too small

  int*   flags = (int*)d_ws;
  float* hws   = (float*)((char*)d_ws + FLAG_BYTES);
  float* wt0   = hws + 4 * HBUF_FLOATS;
  float* wt1   = wt0 + WT_FLOATS;

  // Zero flags + h buffers (h(-1)=c(-1)=0) every call: graph-replay safe.
  hipMemsetAsync(d_ws, 0, FLAG_BYTES + (size_t)4 * HBUF_FLOATS * 4, stream);

  transpose_w<<<dim3(4, 8, 4), 256, 0, stream>>>(k0, wt0);
  transpose_w<<<dim3(4, 8, 4), 256, 0, stream>>>(k1, wt1);

  lstm2_persistent<<<256, NTHREADS, 0, stream>>>(x, b0, b1, wt0, wt1, hws, flags);

  // h2(T-1) lives in buffer [(T-1)&1] = buffer 1
  head_kernel<<<1, 384, 0, stream>>>(hws + 3 * HBUF_FLOATS, w_out, b_out, out);
}